// Round 3
// baseline (959.349 us; speedup 1.0000x reference)
//
#include <hip/hip_runtime.h>

#define N_NODES 80000
#define N_EDGES 1280000
#define IN_CH 128
#define HID 64
#define OUT_CH 32

#define NBUCK 625      // 128 dst-nodes per bucket; 625*128 == 80000 exactly
#define CAP 3072       // bucket capacity; Poisson(mean=2048), 3072 is >20 sigma
#define BIN_BLOCKS 256

// ---------------- binning: edges -> per-dst-bucket arrays ----------------
// packed edge word: src (17 bits) | dstLocal (7 bits) << 17
__global__ __launch_bounds__(256) void k_bin(const int* __restrict__ src,
                                             const int* __restrict__ dst,
                                             int* __restrict__ gcur,
                                             unsigned int* __restrict__ binned) {
    __shared__ int hist[NBUCK];
    __shared__ int lcur[NBUCK];
    int t = threadIdx.x;
    const int chunk = (N_EDGES + BIN_BLOCKS - 1) / BIN_BLOCKS;  // 5000
    int e0 = blockIdx.x * chunk;
    int e1 = min(e0 + chunk, N_EDGES);
    for (int i = t; i < NBUCK; i += 256) hist[i] = 0;
    __syncthreads();
    for (int e = e0 + t; e < e1; e += 256)
        atomicAdd(&hist[dst[e] >> 7], 1);
    __syncthreads();
    for (int i = t; i < NBUCK; i += 256) {
        int h = hist[i];
        lcur[i] = h ? atomicAdd(&gcur[i], h) : 0;
    }
    __syncthreads();
    for (int e = e0 + t; e < e1; e += 256) {
        int d = dst[e];
        int bk = d >> 7;
        int pos = atomicAdd(&lcur[bk], 1);
        if (pos < CAP)
            binned[(size_t)bk * CAP + pos] =
                (unsigned int)src[e] | ((unsigned int)(d & 127) << 17);
    }
}

// ---------------- per-bucket degree -> dinv ----------------
__global__ __launch_bounds__(256) void k_dinv_bin(const unsigned int* __restrict__ binned,
                                                  const int* __restrict__ cnt,
                                                  float* __restrict__ dinv) {
    __shared__ int deg[128];
    int bk = blockIdx.x, t = threadIdx.x;
    if (t < 128) deg[t] = 1;  // self loop
    __syncthreads();
    int n_e = min(cnt[bk], CAP);
    const unsigned int* eb = binned + (size_t)bk * CAP;
    for (int i = t; i < n_e; i += 256) atomicAdd(&deg[eb[i] >> 17], 1);
    __syncthreads();
    if (t < 128) dinv[bk * 128 + t] = rsqrtf((float)deg[t]);
}

// ---------------- GEMM1 (32-col slice): out[n][out_off + 0:32] =
//                  dinv[n] * x[n] @ W1[:, wcol0:wcol0+32] ----------------
__global__ __launch_bounds__(256) void k_gemm1h(const float* __restrict__ x,
                                                const float* __restrict__ W1,
                                                const float* __restrict__ dinv,
                                                float* __restrict__ outg,
                                                int wcol0, int out_stride, int out_off) {
    __shared__ float sX[64 * 132];   // 64 nodes x (128 + pad 4)
    __shared__ float sW[128 * 32];
    int t = threadIdx.x;
    long long nb = (long long)blockIdx.x * 64;
    for (int i = t * 4; i < 128 * 32; i += 1024) {
        int k = i >> 5, c = i & 31;
        *(float4*)&sW[i] = *(const float4*)&W1[k * 64 + wcol0 + c];
    }
    for (int r = 0; r < 8; ++r) {
        int n = (t >> 5) + r * 8;
        int k4 = (t & 31) * 4;
        *(float4*)&sX[n * 132 + k4] = *(const float4*)&x[(nb + n) * IN_CH + k4];
    }
    __syncthreads();
    int tx = t & 7, ty = t >> 3;  // feats tx*4..tx*4+3, nodes ty*2, ty*2+1
    float acc0[4] = {0, 0, 0, 0}, acc1[4] = {0, 0, 0, 0};
#pragma unroll 4
    for (int k = 0; k < 128; ++k) {
        float4 w = *(float4*)&sW[k * 32 + tx * 4];
        float x0 = sX[(ty * 2 + 0) * 132 + k];
        float x1 = sX[(ty * 2 + 1) * 132 + k];
        acc0[0] += x0 * w.x; acc0[1] += x0 * w.y; acc0[2] += x0 * w.z; acc0[3] += x0 * w.w;
        acc1[0] += x1 * w.x; acc1[1] += x1 * w.y; acc1[2] += x1 * w.z; acc1[3] += x1 * w.w;
    }
#pragma unroll
    for (int j = 0; j < 2; ++j) {
        long long n = nb + ty * 2 + j;
        float dn = dinv[n];
        float* a = j ? acc1 : acc0;
        float4 o = {a[0] * dn, a[1] * dn, a[2] * dn, a[3] * dn};
        *(float4*)&outg[n * out_stride + out_off + tx * 4] = o;
    }
}

// ---------------- GEMM2: g2[n] = dinv[n] * h2[n] @ W2  (K=64, F=32) ----------
__global__ __launch_bounds__(256) void k_gemm2(const float* __restrict__ h2,
                                               const float* __restrict__ W2,
                                               const float* __restrict__ dinv,
                                               float* __restrict__ g2) {
    __shared__ float sX[64 * 68];
    __shared__ float sW[64 * 32];
    int t = threadIdx.x;
    long long nb = (long long)blockIdx.x * 64;
    for (int i = t * 4; i < 64 * 32; i += 1024) {
        *(float4*)&sW[i] = *(const float4*)&W2[i];
    }
    for (int r = 0; r < 4; ++r) {
        int n = (t >> 4) + r * 16;
        int k4 = (t & 15) * 4;
        *(float4*)&sX[n * 68 + k4] = *(const float4*)&h2[(nb + n) * HID + k4];
    }
    __syncthreads();
    int tx = t & 7, ty = t >> 3;
    float acc0[4] = {0, 0, 0, 0}, acc1[4] = {0, 0, 0, 0};
#pragma unroll 4
    for (int k = 0; k < 64; ++k) {
        float4 w = *(float4*)&sW[k * 32 + tx * 4];
        float x0 = sX[(ty * 2 + 0) * 68 + k];
        float x1 = sX[(ty * 2 + 1) * 68 + k];
        acc0[0] += x0 * w.x; acc0[1] += x0 * w.y; acc0[2] += x0 * w.z; acc0[3] += x0 * w.w;
        acc1[0] += x1 * w.x; acc1[1] += x1 * w.y; acc1[2] += x1 * w.z; acc1[3] += x1 * w.w;
    }
#pragma unroll
    for (int j = 0; j < 2; ++j) {
        long long n = nb + ty * 2 + j;
        float dn = dinv[n];
        float* a = j ? acc1 : acc0;
        float4 o = {a[0] * dn, a[1] * dn, a[2] * dn, a[3] * dn};
        *(float4*)&g2[n * 32 + tx * 4] = o;
    }
}

// ---------------- bucket aggregation with LDS accumulator ----------------
// out[n*out_stride + out_off + f] = maybe_relu(dinv[n]*(sum_src g[src][f] + g[n][f])
//                                              + bias[out_off+f])
template <int F>
__global__ __launch_bounds__(512) void k_agg(const float* __restrict__ g,
                                             const unsigned int* __restrict__ binned,
                                             const int* __restrict__ cnt,
                                             const float* __restrict__ dinv,
                                             const float* __restrict__ bias,
                                             float* __restrict__ outp,
                                             int out_stride, int out_off, int do_relu) {
    __shared__ float acc[128 * F];
    __shared__ unsigned int stage[2048];
    const int bk = blockIdx.x;
    const int t = threadIdx.x;
    const int nbase = bk * 128;
    const int n_e = min(cnt[bk], CAP);
    const unsigned int* eb = binned + (size_t)bk * CAP;
    for (int i = t; i < 128 * F; i += 512) acc[i] = 0.f;
    __syncthreads();
    const int wave = t >> 6, lane = t & 63;
    for (int c0 = 0; c0 < n_e; c0 += 2048) {
        int cn = min(2048, n_e - c0);
        for (int i = t; i < cn; i += 512) stage[i] = eb[c0 + i];
        __syncthreads();
        if (F == 64) {
            for (int e = wave; e < cn; e += 8) {
                unsigned int p = stage[e];
                int s = p & 0x1FFFF, dL = p >> 17;
                float v = g[(size_t)s * 64 + lane];
                atomicAdd(&acc[dL * 64 + lane], v);
            }
        } else {
            int half = lane >> 5, fo = lane & 31;
            for (int e0 = wave * 2; e0 < cn; e0 += 16) {
                int e = e0 + half;
                if (e < cn) {
                    unsigned int p = stage[e];
                    int s = p & 0x1FFFF, dL = p >> 17;
                    float v = g[(size_t)s * 32 + fo];
                    atomicAdd(&acc[dL * 32 + fo], v);
                }
            }
        }
        __syncthreads();
    }
    for (int i = t; i < 128 * F; i += 512) {
        int nL = i / F, f = i & (F - 1);
        int n = nbase + nL;
        float v = dinv[n] * (acc[i] + g[(size_t)n * F + f]) + bias[out_off + f];
        if (do_relu) v = fmaxf(v, 0.f);
        outp[(size_t)n * out_stride + out_off + f] = v;
    }
}

static inline size_t align256(size_t x) { return (x + 255) & ~(size_t)255; }

extern "C" void kernel_launch(void* const* d_in, const int* in_sizes, int n_in,
                              void* d_out, int out_size, void* d_ws, size_t ws_size,
                              hipStream_t stream) {
    const float* x  = (const float*)d_in[0];
    const int*   ei = (const int*)d_in[1];
    const float* W1 = (const float*)d_in[2];
    const float* b1 = (const float*)d_in[3];
    const float* W2 = (const float*)d_in[4];
    const float* b2 = (const float*)d_in[5];
    float* out = (float*)d_out;

    const int* src = ei;
    const int* dst = ei + N_EDGES;

    // workspace layout
    size_t off = 0;
    char* ws = (char*)d_ws;
    int* gcur = (int*)(ws + off);            off = align256(off + NBUCK * 4);
    unsigned int* binned = (unsigned int*)(ws + off);
                                             off = align256(off + (size_t)NBUCK * CAP * 4);
    float* dinv = (float*)(ws + off);        off = align256(off + (size_t)N_NODES * 4);

    // full path: g1 holds all 64 feats (needs ~49 MB total); else two 32-halves
    size_t off_g = off;
    size_t need_full = off + align256((size_t)N_NODES * HID * 4)
                           + (size_t)N_NODES * HID * 4;
    bool full = ws_size >= need_full;
    size_t gfloats = full ? (size_t)N_NODES * HID : (size_t)N_NODES * 32;
    float* gbuf = (float*)(ws + off_g);      off = align256(off_g + gfloats * 4);
    float* h2 = (float*)(ws + off);

    // --- bin edges + dinv ---
    hipMemsetAsync(gcur, 0, NBUCK * 4, stream);
    k_bin<<<BIN_BLOCKS, 256, 0, stream>>>(src, dst, gcur, binned);
    k_dinv_bin<<<NBUCK, 256, 0, stream>>>(binned, gcur, dinv);

    // --- layer 1 ---
    if (full) {
        k_gemm1h<<<N_NODES / 64, 256, 0, stream>>>(x, W1, dinv, gbuf, 0, HID, 0);
        k_gemm1h<<<N_NODES / 64, 256, 0, stream>>>(x, W1, dinv, gbuf, 32, HID, 32);
        k_agg<64><<<NBUCK, 512, 0, stream>>>(gbuf, binned, gcur, dinv, b1,
                                             h2, HID, 0, 1);
    } else {
        for (int c0 = 0; c0 < HID; c0 += 32) {
            k_gemm1h<<<N_NODES / 64, 256, 0, stream>>>(x, W1, dinv, gbuf, c0, 32, 0);
            k_agg<32><<<NBUCK, 512, 0, stream>>>(gbuf, binned, gcur, dinv, b1,
                                                 h2, HID, c0, 1);
        }
    }

    // --- layer 2 ---
    float* g2 = gbuf;  // reuse
    k_gemm2<<<N_NODES / 64, 256, 0, stream>>>(h2, W2, dinv, g2);
    k_agg<32><<<NBUCK, 512, 0, stream>>>(g2, binned, gcur, dinv, b2,
                                         out, OUT_CH, 0, 0);
}

// Round 4
// 259.879 us; speedup vs baseline: 3.6915x; 3.6915x over previous
//
#include <hip/hip_runtime.h>

#define N_NODES 80000
#define N_EDGES 1280000
#define IN_CH 128
#define HID 64
#define OUT_CH 32

#define NBUCK 625      // 128 dst-nodes per bucket; 625*128 == 80000 exactly
#define CAP 3072       // bucket capacity; Poisson(mean=2048) -> +20 sigma safe
#define BIN_BLOCKS 256

// ---------------- pass 1: bin edges by dst bucket ----------------
// packed word: src (17 bits) | dstLocal (7 bits) << 17
__global__ __launch_bounds__(256) void k_bin(const int* __restrict__ src,
                                             const int* __restrict__ dst,
                                             int* __restrict__ gcur,
                                             unsigned int* __restrict__ binned) {
    __shared__ int hist[NBUCK];
    __shared__ int lcur[NBUCK];
    int t = threadIdx.x;
    const int chunk = (N_EDGES + BIN_BLOCKS - 1) / BIN_BLOCKS;  // 5000
    int e0 = blockIdx.x * chunk;
    int e1 = min(e0 + chunk, N_EDGES);
    for (int i = t; i < NBUCK; i += 256) hist[i] = 0;
    __syncthreads();
    for (int e = e0 + t; e < e1; e += 256)
        atomicAdd(&hist[dst[e] >> 7], 1);
    __syncthreads();
    for (int i = t; i < NBUCK; i += 256) {
        int h = hist[i];
        lcur[i] = h ? atomicAdd(&gcur[i], h) : 0;
    }
    __syncthreads();
    for (int e = e0 + t; e < e1; e += 256) {
        int d = dst[e];
        int bk = d >> 7;
        int pos = atomicAdd(&lcur[bk], 1);
        if (pos < CAP)
            binned[(size_t)bk * CAP + pos] =
                (unsigned int)src[e] | ((unsigned int)(d & 127) << 17);
    }
}

// ---------------- pass 2: per-bucket counting sort -> CSR + dinv ----------------
__global__ __launch_bounds__(256) void k_csr(const unsigned int* __restrict__ binned,
                                             const int* __restrict__ cnt,
                                             int* __restrict__ csr,
                                             int* __restrict__ rs, int* __restrict__ re,
                                             float* __restrict__ dinv) {
    __shared__ int deg[128];
    __shared__ int scan[128];
    __shared__ int cur[128];
    int bk = blockIdx.x, t = threadIdx.x;
    int n_e = min(cnt[bk], CAP);
    const unsigned int* eb = binned + (size_t)bk * CAP;
    if (t < 128) deg[t] = 0;
    __syncthreads();
    for (int i = t; i < n_e; i += 256) atomicAdd(&deg[eb[i] >> 17], 1);
    __syncthreads();
    if (t < 128) scan[t] = deg[t];
    __syncthreads();
    for (int off = 1; off < 128; off <<= 1) {
        int v = (t < 128 && t >= off) ? scan[t - off] : 0;
        __syncthreads();
        if (t < 128) scan[t] += v;
        __syncthreads();
    }
    if (t < 128) {
        int incl = scan[t];
        int s = incl - deg[t];            // exclusive
        cur[t] = s;
        int n = bk * 128 + t;
        int base = bk * CAP;
        rs[n] = base + s;
        re[n] = base + incl;
        dinv[n] = rsqrtf((float)(deg[t] + 1));  // +1 self loop
    }
    __syncthreads();
    for (int i = t; i < n_e; i += 256) {
        unsigned int p = eb[i];
        int dL = p >> 17;
        int pos = atomicAdd(&cur[dL], 1);
        csr[bk * CAP + pos] = (int)(p & 0x1FFFF);
    }
}

// ---------------- GEMM1: g1[n][wc0..wc1) = dinv[n] * x[n] @ W1[:, wc0..wc1) ----
// write col = obase + (c0 - wc0) + tx*4, stride ostride
__global__ __launch_bounds__(256) void k_gemm1(const float* __restrict__ x,
                                               const float* __restrict__ W1,
                                               const float* __restrict__ dinv,
                                               float* __restrict__ outg,
                                               int wc0, int wc1, int ostride, int obase) {
    __shared__ float sX[64 * 132];   // 64 nodes x (128 + pad)
    __shared__ float sW[128 * 32];
    int t = threadIdx.x;
    long long nb = (long long)blockIdx.x * 64;
    for (int r = 0; r < 8; ++r) {
        int n = (t >> 5) + r * 8;
        int k4 = (t & 31) * 4;
        *(float4*)&sX[n * 132 + k4] = *(const float4*)&x[(nb + n) * IN_CH + k4];
    }
    int tx = t & 7, ty = t >> 3;  // cols tx*4..tx*4+3 (rel), nodes ty*2, ty*2+1
    float dn0 = dinv[nb + ty * 2 + 0];
    float dn1 = dinv[nb + ty * 2 + 1];
    for (int c0 = wc0; c0 < wc1; c0 += 32) {
        __syncthreads();  // protects sX (first iter) and sW reuse (later iters)
        for (int i = t * 4; i < 128 * 32; i += 1024) {
            int k = i >> 5, c = i & 31;
            *(float4*)&sW[i] = *(const float4*)&W1[k * 64 + c0 + c];
        }
        __syncthreads();
        float acc0[4] = {0, 0, 0, 0}, acc1[4] = {0, 0, 0, 0};
#pragma unroll 4
        for (int k = 0; k < 128; ++k) {
            float4 w = *(float4*)&sW[k * 32 + tx * 4];
            float x0 = sX[(ty * 2 + 0) * 132 + k];
            float x1 = sX[(ty * 2 + 1) * 132 + k];
            acc0[0] += x0 * w.x; acc0[1] += x0 * w.y; acc0[2] += x0 * w.z; acc0[3] += x0 * w.w;
            acc1[0] += x1 * w.x; acc1[1] += x1 * w.y; acc1[2] += x1 * w.z; acc1[3] += x1 * w.w;
        }
        int col = obase + (c0 - wc0) + tx * 4;
        {
            long long n = nb + ty * 2;
            float4 o = {acc0[0] * dn0, acc0[1] * dn0, acc0[2] * dn0, acc0[3] * dn0};
            *(float4*)&outg[n * ostride + col] = o;
            float4 o1 = {acc1[0] * dn1, acc1[1] * dn1, acc1[2] * dn1, acc1[3] * dn1};
            *(float4*)&outg[(n + 1) * ostride + col] = o1;
        }
    }
}

// ---------------- GEMM2: g2[n] = dinv[n] * h2[n] @ W2  (K=64, F=32) ----------
__global__ __launch_bounds__(256) void k_gemm2(const float* __restrict__ h2,
                                               const float* __restrict__ W2,
                                               const float* __restrict__ dinv,
                                               float* __restrict__ g2) {
    __shared__ float sX[64 * 68];
    __shared__ float sW[64 * 32];
    int t = threadIdx.x;
    long long nb = (long long)blockIdx.x * 64;
    for (int i = t * 4; i < 64 * 32; i += 1024) {
        *(float4*)&sW[i] = *(const float4*)&W2[i];
    }
    for (int r = 0; r < 4; ++r) {
        int n = (t >> 4) + r * 16;
        int k4 = (t & 15) * 4;
        *(float4*)&sX[n * 68 + k4] = *(const float4*)&h2[(nb + n) * HID + k4];
    }
    __syncthreads();
    int tx = t & 7, ty = t >> 3;
    float acc0[4] = {0, 0, 0, 0}, acc1[4] = {0, 0, 0, 0};
#pragma unroll 4
    for (int k = 0; k < 64; ++k) {
        float4 w = *(float4*)&sW[k * 32 + tx * 4];
        float x0 = sX[(ty * 2 + 0) * 68 + k];
        float x1 = sX[(ty * 2 + 1) * 68 + k];
        acc0[0] += x0 * w.x; acc0[1] += x0 * w.y; acc0[2] += x0 * w.z; acc0[3] += x0 * w.w;
        acc1[0] += x1 * w.x; acc1[1] += x1 * w.y; acc1[2] += x1 * w.z; acc1[3] += x1 * w.w;
    }
#pragma unroll
    for (int j = 0; j < 2; ++j) {
        long long n = nb + ty * 2 + j;
        float dn = dinv[n];
        float* a = j ? acc1 : acc0;
        float4 o = {a[0] * dn, a[1] * dn, a[2] * dn, a[3] * dn};
        *(float4*)&g2[n * 32 + tx * 4] = o;
    }
}

// ---------------- wave-per-node CSR gather aggregation ----------------
// out[n*ostride + obase + f] = maybe_relu(dinv[n]*(g[n][f] + sum g[src][f]) + bias[obase+f])
template <int F>
__global__ __launch_bounds__(256) void k_agg(const float* __restrict__ g,
                                             const int* __restrict__ csr,
                                             const int* __restrict__ rs_,
                                             const int* __restrict__ re_,
                                             const float* __restrict__ dinv,
                                             const float* __restrict__ bias,
                                             float* __restrict__ outp,
                                             int ostride, int obase, int do_relu) {
    int n = blockIdx.x * 4 + (threadIdx.x >> 6);
    int lane = threadIdx.x & 63;
    int a = rs_[n], b = re_[n];
    if (F == 64) {
        float acc = g[(size_t)n * 64 + lane];
        int e = a;
        for (; e + 3 < b; e += 4) {
            int s0 = csr[e], s1 = csr[e + 1], s2 = csr[e + 2], s3 = csr[e + 3];
            float v0 = g[(size_t)s0 * 64 + lane];
            float v1 = g[(size_t)s1 * 64 + lane];
            float v2 = g[(size_t)s2 * 64 + lane];
            float v3 = g[(size_t)s3 * 64 + lane];
            acc += v0 + v1 + v2 + v3;
        }
        for (; e < b; ++e) acc += g[(size_t)csr[e] * 64 + lane];
        float v = dinv[n] * acc + bias[obase + lane];
        if (do_relu) v = fmaxf(v, 0.f);
        outp[(size_t)n * ostride + obase + lane] = v;
    } else {
        int half = lane >> 5, fo = lane & 31;
        float acc = half ? 0.f : g[(size_t)n * 32 + fo];
        int e = a + half;
        for (; e + 6 < b; e += 8) {
            int s0 = csr[e], s1 = csr[e + 2], s2 = csr[e + 4], s3 = csr[e + 6];
            float v0 = g[(size_t)s0 * 32 + fo];
            float v1 = g[(size_t)s1 * 32 + fo];
            float v2 = g[(size_t)s2 * 32 + fo];
            float v3 = g[(size_t)s3 * 32 + fo];
            acc += v0 + v1 + v2 + v3;
        }
        for (; e < b; e += 2) acc += g[(size_t)csr[e] * 32 + fo];
        acc += __shfl_down(acc, 32);
        if (half == 0) {
            float v = dinv[n] * acc + bias[obase + fo];
            if (do_relu) v = fmaxf(v, 0.f);
            outp[(size_t)n * ostride + obase + fo] = v;
        }
    }
}

static inline size_t align256(size_t x) { return (x + 255) & ~(size_t)255; }

extern "C" void kernel_launch(void* const* d_in, const int* in_sizes, int n_in,
                              void* d_out, int out_size, void* d_ws, size_t ws_size,
                              hipStream_t stream) {
    const float* x  = (const float*)d_in[0];
    const int*   ei = (const int*)d_in[1];
    const float* W1 = (const float*)d_in[2];
    const float* b1 = (const float*)d_in[3];
    const float* W2 = (const float*)d_in[4];
    const float* b2 = (const float*)d_in[5];
    float* out = (float*)d_out;

    const int* src = ei;
    const int* dst = ei + N_EDGES;

    // workspace layout; binned aliases gbuf (consumed by k_csr before gemm writes)
    char* ws = (char*)d_ws;
    size_t off = 0;
    int* gcur = (int*)(ws + off);          off = align256(off + NBUCK * 4);
    int* csr  = (int*)(ws + off);          off = align256(off + (size_t)NBUCK * CAP * 4);
    int* rs   = (int*)(ws + off);          off = align256(off + (size_t)N_NODES * 4);
    int* re   = (int*)(ws + off);          off = align256(off + (size_t)N_NODES * 4);
    float* dinv = (float*)(ws + off);      off = align256(off + (size_t)N_NODES * 4);
    float* h2 = (float*)(ws + off);        off = align256(off + (size_t)N_NODES * HID * 4);
    size_t off_g = off;
    size_t need_full = off + (size_t)N_NODES * HID * 4;
    bool full = ws_size >= need_full;      // gbuf [N,64] vs [N,32]
    float* gbuf = (float*)(ws + off_g);
    unsigned int* binned = (unsigned int*)gbuf;  // NBUCK*CAP*4 = 7.68MB <= gbuf size

    // --- build CSR ---
    hipMemsetAsync(gcur, 0, NBUCK * 4, stream);
    k_bin<<<BIN_BLOCKS, 256, 0, stream>>>(src, dst, gcur, binned);
    k_csr<<<NBUCK, 256, 0, stream>>>(binned, gcur, csr, rs, re, dinv);

    // --- layer 1 ---
    if (full) {
        k_gemm1<<<N_NODES / 64, 256, 0, stream>>>(x, W1, dinv, gbuf, 0, HID, HID, 0);
        k_agg<64><<<N_NODES / 4, 256, 0, stream>>>(gbuf, csr, rs, re, dinv, b1,
                                                   h2, HID, 0, 1);
    } else {
        for (int c0 = 0; c0 < HID; c0 += 32) {
            k_gemm1<<<N_NODES / 64, 256, 0, stream>>>(x, W1, dinv, gbuf, c0, c0 + 32, 32, 0);
            k_agg<32><<<N_NODES / 4, 256, 0, stream>>>(gbuf, csr, rs, re, dinv, b1,
                                                       h2, HID, c0, 1);
        }
    }

    // --- layer 2 ---
    float* g2 = gbuf;  // reuse
    k_gemm2<<<N_NODES / 64, 256, 0, stream>>>(h2, W2, dinv, g2);
    k_agg<32><<<N_NODES / 4, 256, 0, stream>>>(g2, csr, rs, re, dinv, b2,
                                               out, OUT_CH, 0, 0);
}

// Round 5
// 241.083 us; speedup vs baseline: 3.9793x; 1.0780x over previous
//
#include <hip/hip_runtime.h>

#define N_NODES 80000
#define N_EDGES 1280000
#define IN_CH 128
#define HID 64
#define OUT_CH 32

#define NBUCK 625      // 128 dst-nodes per bucket; 625*128 == 80000
#define CAP 3072       // bucket capacity; Poisson(mean=2048) -> +20 sigma safe
#define BIN_BLOCKS 256

// ---- bf16 pack/unpack helpers (RNE) ----
__device__ __forceinline__ float bl(unsigned u) { return __uint_as_float(u << 16); }
__device__ __forceinline__ float bh(unsigned u) { return __uint_as_float(u & 0xFFFF0000u); }
__device__ __forceinline__ unsigned bf16rn(float x) {
    unsigned u = __float_as_uint(x);
    return (u + 0x7FFFu + ((u >> 16) & 1u)) >> 16;
}
__device__ __forceinline__ unsigned pack2(float a, float b) {
    return bf16rn(a) | (bf16rn(b) << 16);
}

// ---------------- pass 1: bin edges by dst bucket ----------------
// packed word: src (17 bits) | dstLocal (7 bits) << 17
__global__ __launch_bounds__(256) void k_bin(const int* __restrict__ src,
                                             const int* __restrict__ dst,
                                             int* __restrict__ gcur,
                                             unsigned int* __restrict__ binned) {
    __shared__ int hist[NBUCK];
    __shared__ int lcur[NBUCK];
    int t = threadIdx.x;
    const int chunk = N_EDGES / BIN_BLOCKS;  // 5000
    int e0 = blockIdx.x * chunk;
    int e1 = e0 + chunk;
    for (int i = t; i < NBUCK; i += 256) hist[i] = 0;
    __syncthreads();
    for (int e = e0 + t; e < e1; e += 256)
        atomicAdd(&hist[dst[e] >> 7], 1);
    __syncthreads();
    for (int i = t; i < NBUCK; i += 256) {
        int h = hist[i];
        lcur[i] = h ? atomicAdd(&gcur[i], h) : 0;
    }
    __syncthreads();
    for (int e = e0 + t; e < e1; e += 256) {
        int d = dst[e];
        int bk = d >> 7;
        int pos = atomicAdd(&lcur[bk], 1);
        if (pos < CAP)
            binned[(size_t)bk * CAP + pos] =
                (unsigned int)src[e] | ((unsigned int)(d & 127) << 17);
    }
}

// ---------------- fused: CSR build (blocks 0..624) + GEMM1 (blocks 625..1874) ----
// CSR: per-bucket counting sort -> csr (src only), rs/re, dinv
// GEMM1: h1[n][:] = x[n] @ W1 (UNSCALED), packed bf16 pairs
__global__ __launch_bounds__(256) void k_csr_gemm1(
        const unsigned int* __restrict__ binned, const int* __restrict__ cnt,
        int* __restrict__ csr, int* __restrict__ rs, int* __restrict__ re,
        float* __restrict__ dinv,
        const float* __restrict__ x, const float* __restrict__ W1,
        unsigned int* __restrict__ h1u) {
    __shared__ float smem[64 * 132 + 128 * 32];  // 50176 B (gemm needs all of it)
    int bid = blockIdx.x, t = threadIdx.x;
    if (bid < NBUCK) {
        // ---- CSR path ----
        int* deg = (int*)smem;
        int* scan = deg + 128;
        int* cur = scan + 128;
        int bk = bid;
        int n_e = min(cnt[bk], CAP);
        const unsigned int* eb = binned + (size_t)bk * CAP;
        if (t < 128) deg[t] = 0;
        __syncthreads();
        for (int i = t; i < n_e; i += 256) atomicAdd(&deg[eb[i] >> 17], 1);
        __syncthreads();
        if (t < 128) scan[t] = deg[t];
        __syncthreads();
        for (int off = 1; off < 128; off <<= 1) {
            int v = (t < 128 && t >= off) ? scan[t - off] : 0;
            __syncthreads();
            if (t < 128) scan[t] += v;
            __syncthreads();
        }
        if (t < 128) {
            int incl = scan[t];
            int s = incl - deg[t];
            cur[t] = s;
            int n = bk * 128 + t;
            int base = bk * CAP;
            rs[n] = base + s;
            re[n] = base + incl;
            dinv[n] = rsqrtf((float)(deg[t] + 1));  // +1 self loop
        }
        __syncthreads();
        for (int i = t; i < n_e; i += 256) {
            unsigned int p = eb[i];
            int dL = p >> 17;
            int pos = atomicAdd(&cur[dL], 1);
            csr[bk * CAP + pos] = (int)(p & 0x1FFFF);
        }
    } else {
        // ---- GEMM1 path ----
        float* sX = smem;                 // 64 x 132
        float* sW = smem + 64 * 132;      // 128 x 32
        long long nb = (long long)(bid - NBUCK) * 64;
        for (int r = 0; r < 8; ++r) {
            int n = (t >> 5) + r * 8;
            int k4 = (t & 31) * 4;
            *(float4*)&sX[n * 132 + k4] = *(const float4*)&x[(nb + n) * IN_CH + k4];
        }
        int tx = t & 7, ty = t >> 3;  // cols tx*4.., nodes ty*2, ty*2+1
        for (int c0 = 0; c0 < HID; c0 += 32) {
            __syncthreads();
            for (int i = t * 4; i < 128 * 32; i += 1024) {
                int k = i >> 5, c = i & 31;
                *(float4*)&sW[i] = *(const float4*)&W1[k * 64 + c0 + c];
            }
            __syncthreads();
            float acc0[4] = {0, 0, 0, 0}, acc1[4] = {0, 0, 0, 0};
#pragma unroll 4
            for (int k = 0; k < 128; ++k) {
                float4 w = *(float4*)&sW[k * 32 + tx * 4];
                float x0 = sX[(ty * 2 + 0) * 132 + k];
                float x1 = sX[(ty * 2 + 1) * 132 + k];
                acc0[0] += x0 * w.x; acc0[1] += x0 * w.y; acc0[2] += x0 * w.z; acc0[3] += x0 * w.w;
                acc1[0] += x1 * w.x; acc1[1] += x1 * w.y; acc1[2] += x1 * w.z; acc1[3] += x1 * w.w;
            }
            int cu = (c0 >> 1) + tx * 2;  // uint index of col pair
            long long n = nb + ty * 2;
            uint2 p0 = {pack2(acc0[0], acc0[1]), pack2(acc0[2], acc0[3])};
            *(uint2*)&h1u[n * 32 + cu] = p0;
            uint2 p1 = {pack2(acc1[0], acc1[1]), pack2(acc1[2], acc1[3])};
            *(uint2*)&h1u[(n + 1) * 32 + cu] = p1;
        }
    }
}

// ---------------- agg layer 1: F=64, bf16 table, wave = 2 edges in flight -----
// h2[n][f] = relu(dinv[n] * (dinv[n]*h1[n][f] + sum_s dinv[s]*h1[s][f]) + b1[f])
__global__ __launch_bounds__(256) void k_agg64(
        const unsigned int* __restrict__ h1u, const int* __restrict__ csr,
        const int* __restrict__ rs_, const int* __restrict__ re_,
        const float* __restrict__ dinv, const float* __restrict__ b1,
        float* __restrict__ h2) {
    int n = blockIdx.x * 4 + (threadIdx.x >> 6);
    int lane = threadIdx.x & 63;
    int half = lane >> 5, fo = lane & 31;  // feats 2fo, 2fo+1
    int a = rs_[n], b = re_[n];
    float ax = 0.f, ay = 0.f;
    int e = a + half;
    for (; e + 6 < b; e += 8) {
        int s0 = csr[e], s1 = csr[e + 2], s2 = csr[e + 4], s3 = csr[e + 6];
        unsigned u0 = h1u[(size_t)s0 * 32 + fo]; float d0 = dinv[s0];
        unsigned u1 = h1u[(size_t)s1 * 32 + fo]; float d1 = dinv[s1];
        unsigned u2 = h1u[(size_t)s2 * 32 + fo]; float d2 = dinv[s2];
        unsigned u3 = h1u[(size_t)s3 * 32 + fo]; float d3 = dinv[s3];
        ax += d0 * bl(u0); ay += d0 * bh(u0);
        ax += d1 * bl(u1); ay += d1 * bh(u1);
        ax += d2 * bl(u2); ay += d2 * bh(u2);
        ax += d3 * bl(u3); ay += d3 * bh(u3);
    }
    for (; e < b; e += 2) {
        int s = csr[e];
        unsigned u = h1u[(size_t)s * 32 + fo];
        float d = dinv[s];
        ax += d * bl(u); ay += d * bh(u);
    }
    ax += __shfl_down(ax, 32);
    ay += __shfl_down(ay, 32);
    if (half == 0) {
        float dn = dinv[n];
        unsigned un = h1u[(size_t)n * 32 + fo];
        ax += dn * bl(un); ay += dn * bh(un);   // self loop
        float2 bb = *(const float2*)&b1[2 * fo];
        float vx = dn * ax + bb.x, vy = dn * ay + bb.y;
        vx = fmaxf(vx, 0.f); vy = fmaxf(vy, 0.f);
        float2 o = {vx, vy};
        *(float2*)&h2[(size_t)n * 64 + 2 * fo] = o;
    }
}

// ---------------- GEMM2: g2[n] = h2[n] @ W2 (UNSCALED), bf16 packed ----------
__global__ __launch_bounds__(256) void k_gemm2(const float* __restrict__ h2,
                                               const float* __restrict__ W2,
                                               unsigned int* __restrict__ g2u) {
    __shared__ float sX[64 * 68];
    __shared__ float sW[64 * 32];
    int t = threadIdx.x;
    long long nb = (long long)blockIdx.x * 64;
    for (int i = t * 4; i < 64 * 32; i += 1024) {
        *(float4*)&sW[i] = *(const float4*)&W2[i];
    }
    for (int r = 0; r < 4; ++r) {
        int n = (t >> 4) + r * 16;
        int k4 = (t & 15) * 4;
        *(float4*)&sX[n * 68 + k4] = *(const float4*)&h2[(nb + n) * HID + k4];
    }
    __syncthreads();
    int tx = t & 7, ty = t >> 3;
    float acc0[4] = {0, 0, 0, 0}, acc1[4] = {0, 0, 0, 0};
#pragma unroll 4
    for (int k = 0; k < 64; ++k) {
        float4 w = *(float4*)&sW[k * 32 + tx * 4];
        float x0 = sX[(ty * 2 + 0) * 68 + k];
        float x1 = sX[(ty * 2 + 1) * 68 + k];
        acc0[0] += x0 * w.x; acc0[1] += x0 * w.y; acc0[2] += x0 * w.z; acc0[3] += x0 * w.w;
        acc1[0] += x1 * w.x; acc1[1] += x1 * w.y; acc1[2] += x1 * w.z; acc1[3] += x1 * w.w;
    }
    long long n = nb + ty * 2;
    uint2 p0 = {pack2(acc0[0], acc0[1]), pack2(acc0[2], acc0[3])};
    *(uint2*)&g2u[n * 16 + tx * 2] = p0;
    uint2 p1 = {pack2(acc1[0], acc1[1]), pack2(acc1[2], acc1[3])};
    *(uint2*)&g2u[(n + 1) * 16 + tx * 2] = p1;
}

// ---------------- agg layer 2: F=32, bf16 table, wave = 4 edges in flight -----
__global__ __launch_bounds__(256) void k_agg32(
        const unsigned int* __restrict__ g2u, const int* __restrict__ csr,
        const int* __restrict__ rs_, const int* __restrict__ re_,
        const float* __restrict__ dinv, const float* __restrict__ b2,
        float* __restrict__ outp) {
    int n = blockIdx.x * 4 + (threadIdx.x >> 6);
    int lane = threadIdx.x & 63;
    int q = lane >> 4, fo = lane & 15;  // feats 2fo, 2fo+1
    int a = rs_[n], b = re_[n];
    float ax = 0.f, ay = 0.f;
    int e = a + q;
    for (; e + 12 < b; e += 16) {
        int s0 = csr[e], s1 = csr[e + 4], s2 = csr[e + 8], s3 = csr[e + 12];
        unsigned u0 = g2u[(size_t)s0 * 16 + fo]; float d0 = dinv[s0];
        unsigned u1 = g2u[(size_t)s1 * 16 + fo]; float d1 = dinv[s1];
        unsigned u2 = g2u[(size_t)s2 * 16 + fo]; float d2 = dinv[s2];
        unsigned u3 = g2u[(size_t)s3 * 16 + fo]; float d3 = dinv[s3];
        ax += d0 * bl(u0); ay += d0 * bh(u0);
        ax += d1 * bl(u1); ay += d1 * bh(u1);
        ax += d2 * bl(u2); ay += d2 * bh(u2);
        ax += d3 * bl(u3); ay += d3 * bh(u3);
    }
    for (; e < b; e += 4) {
        int s = csr[e];
        unsigned u = g2u[(size_t)s * 16 + fo];
        float d = dinv[s];
        ax += d * bl(u); ay += d * bh(u);
    }
    ax += __shfl_down(ax, 32); ay += __shfl_down(ay, 32);
    ax += __shfl_down(ax, 16); ay += __shfl_down(ay, 16);
    if (q == 0) {
        float dn = dinv[n];
        unsigned un = g2u[(size_t)n * 16 + fo];
        ax += dn * bl(un); ay += dn * bh(un);   // self loop
        float2 bb = *(const float2*)&b2[2 * fo];
        float2 o = {dn * ax + bb.x, dn * ay + bb.y};
        *(float2*)&outp[(size_t)n * 32 + 2 * fo] = o;
    }
}

static inline size_t align256(size_t x) { return (x + 255) & ~(size_t)255; }

extern "C" void kernel_launch(void* const* d_in, const int* in_sizes, int n_in,
                              void* d_out, int out_size, void* d_ws, size_t ws_size,
                              hipStream_t stream) {
    const float* x  = (const float*)d_in[0];
    const int*   ei = (const int*)d_in[1];
    const float* W1 = (const float*)d_in[2];
    const float* b1 = (const float*)d_in[3];
    const float* W2 = (const float*)d_in[4];
    const float* b2 = (const float*)d_in[5];
    float* out = (float*)d_out;

    const int* src = ei;
    const int* dst = ei + N_EDGES;

    // workspace layout (peak 47.04 MB; ws >= ~48.97 MB proven by R3 full path)
    char* ws = (char*)d_ws;
    size_t off = 0;
    int* gcur = (int*)(ws + off);              off = align256(off + NBUCK * 4);
    unsigned int* binned = (unsigned int*)(ws + off);
                                               off = align256(off + (size_t)NBUCK * CAP * 4);
    int* csr = (int*)(ws + off);               off = align256(off + (size_t)NBUCK * CAP * 4);
    int* rs  = (int*)(ws + off);               off = align256(off + (size_t)N_NODES * 4);
    int* re  = (int*)(ws + off);               off = align256(off + (size_t)N_NODES * 4);
    float* dinv = (float*)(ws + off);          off = align256(off + (size_t)N_NODES * 4);
    unsigned int* h1u = (unsigned int*)(ws + off);
                                               off = align256(off + (size_t)N_NODES * 32 * 4);
    float* h2 = (float*)(ws + off);            off = align256(off + (size_t)N_NODES * HID * 4);
    unsigned int* g2u = h1u;  // reuse (5.12 MB <= 10.24 MB), h1u dead after agg64

    hipMemsetAsync(gcur, 0, NBUCK * 4, stream);
    k_bin<<<BIN_BLOCKS, 256, 0, stream>>>(src, dst, gcur, binned);
    k_csr_gemm1<<<NBUCK + N_NODES / 64, 256, 0, stream>>>(binned, gcur, csr, rs, re,
                                                          dinv, x, W1, h1u);
    k_agg64<<<N_NODES / 4, 256, 0, stream>>>(h1u, csr, rs, re, dinv, b1, h2);
    k_gemm2<<<N_NODES / 64, 256, 0, stream>>>(h2, W2, g2u);
    k_agg32<<<N_NODES / 4, 256, 0, stream>>>(g2u, csr, rs, re, dinv, b2, out);
}

// Round 6
// 233.206 us; speedup vs baseline: 4.1137x; 1.0338x over previous
//
#include <hip/hip_runtime.h>

#define N_NODES 80000
#define N_EDGES 1280000
#define IN_CH 128
#define HID 64
#define OUT_CH 32

#define NBUCK 625      // 128 dst-nodes per bucket; 625*128 == 80000
#define CAP 3072       // bucket capacity; Poisson(mean=2048) -> +20 sigma safe
#define BIN_BLOCKS 256

// ---- bf16 pack/unpack helpers (RNE) ----
__device__ __forceinline__ float bl(unsigned u) { return __uint_as_float(u << 16); }
__device__ __forceinline__ float bh(unsigned u) { return __uint_as_float(u & 0xFFFF0000u); }
__device__ __forceinline__ unsigned bf16rn(float x) {
    unsigned u = __float_as_uint(x);
    return (u + 0x7FFFu + ((u >> 16) & 1u)) >> 16;
}
__device__ __forceinline__ unsigned pack2(float a, float b) {
    return bf16rn(a) | (bf16rn(b) << 16);
}

// ---------------- pass 1: bin edges by dst bucket ----------------
// packed word: src (17 bits) | dstLocal (7 bits) << 17
__global__ __launch_bounds__(256) void k_bin(const int* __restrict__ src,
                                             const int* __restrict__ dst,
                                             int* __restrict__ gcur,
                                             unsigned int* __restrict__ binned) {
    __shared__ int hist[NBUCK];
    __shared__ int lcur[NBUCK];
    int t = threadIdx.x;
    const int chunk = N_EDGES / BIN_BLOCKS;  // 5000
    int e0 = blockIdx.x * chunk;
    int e1 = e0 + chunk;
    for (int i = t; i < NBUCK; i += 256) hist[i] = 0;
    __syncthreads();
    for (int e = e0 + t; e < e1; e += 256)
        atomicAdd(&hist[dst[e] >> 7], 1);
    __syncthreads();
    for (int i = t; i < NBUCK; i += 256) {
        int h = hist[i];
        lcur[i] = h ? atomicAdd(&gcur[i], h) : 0;
    }
    __syncthreads();
    for (int e = e0 + t; e < e1; e += 256) {
        int d = dst[e];
        int bk = d >> 7;
        int pos = atomicAdd(&lcur[bk], 1);
        if (pos < CAP)
            binned[(size_t)bk * CAP + pos] =
                (unsigned int)src[e] | ((unsigned int)(d & 127) << 17);
    }
}

// ---------------- fused: CSR build (blocks 0..624) + GEMM1 (blocks 625..1249) ----
// CSR: per-bucket counting sort -> csr (src only), rs/re, dinv
// GEMM1: h1[n][:] = x[n] @ W1 (UNSCALED), packed bf16 pairs. 128 nodes/block,
// 4 nodes x 8 cols per thread, K in two 64-halves, float4 k-step reads.
__global__ __launch_bounds__(256) void k_csr_gemm1(
        const unsigned int* __restrict__ binned, const int* __restrict__ cnt,
        int* __restrict__ csr, int* __restrict__ rs, int* __restrict__ re,
        float* __restrict__ dinv,
        const float* __restrict__ x, const float* __restrict__ W1,
        unsigned int* __restrict__ h1u) {
    __shared__ float smem[12800];  // 51200 B: sX 128x68 (8704 f) + sW 64x64 (4096 f)
    int bid = blockIdx.x, t = threadIdx.x;
    if (bid < NBUCK) {
        // ---- CSR path ----
        int* deg = (int*)smem;
        int* scan = deg + 128;
        int* cur = scan + 128;
        int bk = bid;
        int n_e = min(cnt[bk], CAP);
        const unsigned int* eb = binned + (size_t)bk * CAP;
        if (t < 128) deg[t] = 0;
        __syncthreads();
        for (int i = t; i < n_e; i += 256) atomicAdd(&deg[eb[i] >> 17], 1);
        __syncthreads();
        if (t < 128) scan[t] = deg[t];
        __syncthreads();
        for (int off = 1; off < 128; off <<= 1) {
            int v = (t < 128 && t >= off) ? scan[t - off] : 0;
            __syncthreads();
            if (t < 128) scan[t] += v;
            __syncthreads();
        }
        if (t < 128) {
            int incl = scan[t];
            int s = incl - deg[t];
            cur[t] = s;
            int n = bk * 128 + t;
            int base = bk * CAP;
            rs[n] = base + s;
            re[n] = base + incl;
            dinv[n] = rsqrtf((float)(deg[t] + 1));  // +1 self loop
        }
        __syncthreads();
        for (int i = t; i < n_e; i += 256) {
            unsigned int p = eb[i];
            int dL = p >> 17;
            int pos = atomicAdd(&cur[dL], 1);
            csr[bk * CAP + pos] = (int)(p & 0x1FFFF);
        }
    } else {
        // ---- GEMM1 path ----
        float* sX = smem;             // 128 x 68 (pad keeps 16B align, spreads banks)
        float* sW = smem + 128 * 68;  // 64 x 64
        long long nb = (long long)(bid - NBUCK) * 128;
        int tx2 = t & 31, tc = t >> 5;     // nodes {tx2+32i}, cols tc*8..tc*8+7
        float acc[4][8];
#pragma unroll
        for (int i = 0; i < 4; ++i)
#pragma unroll
            for (int c = 0; c < 8; ++c) acc[i][c] = 0.f;
        for (int H = 0; H < 2; ++H) {
            int k0 = H * 64;
            __syncthreads();
#pragma unroll
            for (int r = 0; r < 8; ++r) {   // stage x: 128 nodes x 64 k
                int idx = t + r * 256;
                int node = idx >> 4, k4 = (idx & 15) * 4;
                *(float4*)&sX[node * 68 + k4] =
                    *(const float4*)&x[(nb + node) * IN_CH + k0 + k4];
            }
#pragma unroll
            for (int r = 0; r < 4; ++r) {   // stage W: 64 k x 64 c
                int idx = t + r * 256;
                int k = idx >> 4, c4 = (idx & 15) * 4;
                *(float4*)&sW[k * 64 + c4] = *(const float4*)&W1[(k0 + k) * 64 + c4];
            }
            __syncthreads();
            for (int kk = 0; kk < 64; kk += 4) {
                float4 xv[4];
#pragma unroll
                for (int i = 0; i < 4; ++i)
                    xv[i] = *(float4*)&sX[(tx2 + 32 * i) * 68 + kk];
#pragma unroll
                for (int j = 0; j < 4; ++j) {
                    float4 wa = *(float4*)&sW[(kk + j) * 64 + tc * 8];
                    float4 wb = *(float4*)&sW[(kk + j) * 64 + tc * 8 + 4];
#pragma unroll
                    for (int i = 0; i < 4; ++i) {
                        float xs = ((const float*)&xv[i])[j];
                        acc[i][0] += xs * wa.x; acc[i][1] += xs * wa.y;
                        acc[i][2] += xs * wa.z; acc[i][3] += xs * wa.w;
                        acc[i][4] += xs * wb.x; acc[i][5] += xs * wb.y;
                        acc[i][6] += xs * wb.z; acc[i][7] += xs * wb.w;
                    }
                }
            }
        }
#pragma unroll
        for (int i = 0; i < 4; ++i) {
            long long node = nb + tx2 + 32 * i;
            uint4 pv = {pack2(acc[i][0], acc[i][1]), pack2(acc[i][2], acc[i][3]),
                        pack2(acc[i][4], acc[i][5]), pack2(acc[i][6], acc[i][7])};
            *(uint4*)&h1u[node * 32 + tc * 4] = pv;
        }
    }
}

// ---------------- agg layer 1: F=64, bf16 table, wave = 2 edges in flight -----
// h2[n][f] = relu(dinv[n] * (dinv[n]*h1[n][f] + sum_s dinv[s]*h1[s][f]) + b1[f])
__global__ __launch_bounds__(256) void k_agg64(
        const unsigned int* __restrict__ h1u, const int* __restrict__ csr,
        const int* __restrict__ rs_, const int* __restrict__ re_,
        const float* __restrict__ dinv, const float* __restrict__ b1,
        float* __restrict__ h2) {
    int n = blockIdx.x * 4 + (threadIdx.x >> 6);
    int lane = threadIdx.x & 63;
    int half = lane >> 5, fo = lane & 31;  // feats 2fo, 2fo+1
    int a = rs_[n], b = re_[n];
    float ax = 0.f, ay = 0.f;
    int e = a + half;
    for (; e + 6 < b; e += 8) {
        int s0 = csr[e], s1 = csr[e + 2], s2 = csr[e + 4], s3 = csr[e + 6];
        unsigned u0 = h1u[(size_t)s0 * 32 + fo]; float d0 = dinv[s0];
        unsigned u1 = h1u[(size_t)s1 * 32 + fo]; float d1 = dinv[s1];
        unsigned u2 = h1u[(size_t)s2 * 32 + fo]; float d2 = dinv[s2];
        unsigned u3 = h1u[(size_t)s3 * 32 + fo]; float d3 = dinv[s3];
        ax += d0 * bl(u0); ay += d0 * bh(u0);
        ax += d1 * bl(u1); ay += d1 * bh(u1);
        ax += d2 * bl(u2); ay += d2 * bh(u2);
        ax += d3 * bl(u3); ay += d3 * bh(u3);
    }
    for (; e < b; e += 2) {
        int s = csr[e];
        unsigned u = h1u[(size_t)s * 32 + fo];
        float d = dinv[s];
        ax += d * bl(u); ay += d * bh(u);
    }
    ax += __shfl_down(ax, 32);
    ay += __shfl_down(ay, 32);
    if (half == 0) {
        float dn = dinv[n];
        unsigned un = h1u[(size_t)n * 32 + fo];
        ax += dn * bl(un); ay += dn * bh(un);   // self loop
        float2 bb = *(const float2*)&b1[2 * fo];
        float vx = dn * ax + bb.x, vy = dn * ay + bb.y;
        vx = fmaxf(vx, 0.f); vy = fmaxf(vy, 0.f);
        float2 o = {vx, vy};
        *(float2*)&h2[(size_t)n * 64 + 2 * fo] = o;
    }
}

// ---------------- GEMM2: g2[n] = h2[n] @ W2 (UNSCALED), bf16 packed ----------
__global__ __launch_bounds__(256) void k_gemm2(const float* __restrict__ h2,
                                               const float* __restrict__ W2,
                                               unsigned int* __restrict__ g2u) {
    __shared__ float sX[64 * 68];
    __shared__ float sW[64 * 32];
    int t = threadIdx.x;
    long long nb = (long long)blockIdx.x * 64;
    for (int i = t * 4; i < 64 * 32; i += 1024) {
        *(float4*)&sW[i] = *(const float4*)&W2[i];
    }
    for (int r = 0; r < 4; ++r) {
        int n = (t >> 4) + r * 16;
        int k4 = (t & 15) * 4;
        *(float4*)&sX[n * 68 + k4] = *(const float4*)&h2[(nb + n) * HID + k4];
    }
    __syncthreads();
    int tx = t & 7, ty = t >> 3;
    float acc0[4] = {0, 0, 0, 0}, acc1[4] = {0, 0, 0, 0};
#pragma unroll 4
    for (int k = 0; k < 64; ++k) {
        float4 w = *(float4*)&sW[k * 32 + tx * 4];
        float x0 = sX[(ty * 2 + 0) * 68 + k];
        float x1 = sX[(ty * 2 + 1) * 68 + k];
        acc0[0] += x0 * w.x; acc0[1] += x0 * w.y; acc0[2] += x0 * w.z; acc0[3] += x0 * w.w;
        acc1[0] += x1 * w.x; acc1[1] += x1 * w.y; acc1[2] += x1 * w.z; acc1[3] += x1 * w.w;
    }
    long long n = nb + ty * 2;
    uint2 p0 = {pack2(acc0[0], acc0[1]), pack2(acc0[2], acc0[3])};
    *(uint2*)&g2u[n * 16 + tx * 2] = p0;
    uint2 p1 = {pack2(acc1[0], acc1[1]), pack2(acc1[2], acc1[3])};
    *(uint2*)&g2u[(n + 1) * 16 + tx * 2] = p1;
}

// ---------------- agg layer 2: F=32, bf16 table, wave = 4 edges in flight -----
__global__ __launch_bounds__(256) void k_agg32(
        const unsigned int* __restrict__ g2u, const int* __restrict__ csr,
        const int* __restrict__ rs_, const int* __restrict__ re_,
        const float* __restrict__ dinv, const float* __restrict__ b2,
        float* __restrict__ outp) {
    int n = blockIdx.x * 4 + (threadIdx.x >> 6);
    int lane = threadIdx.x & 63;
    int q = lane >> 4, fo = lane & 15;  // feats 2fo, 2fo+1
    int a = rs_[n], b = re_[n];
    float ax = 0.f, ay = 0.f;
    int e = a + q;
    for (; e + 12 < b; e += 16) {
        int s0 = csr[e], s1 = csr[e + 4], s2 = csr[e + 8], s3 = csr[e + 12];
        unsigned u0 = g2u[(size_t)s0 * 16 + fo]; float d0 = dinv[s0];
        unsigned u1 = g2u[(size_t)s1 * 16 + fo]; float d1 = dinv[s1];
        unsigned u2 = g2u[(size_t)s2 * 16 + fo]; float d2 = dinv[s2];
        unsigned u3 = g2u[(size_t)s3 * 16 + fo]; float d3 = dinv[s3];
        ax += d0 * bl(u0); ay += d0 * bh(u0);
        ax += d1 * bl(u1); ay += d1 * bh(u1);
        ax += d2 * bl(u2); ay += d2 * bh(u2);
        ax += d3 * bl(u3); ay += d3 * bh(u3);
    }
    for (; e < b; e += 4) {
        int s = csr[e];
        unsigned u = g2u[(size_t)s * 16 + fo];
        float d = dinv[s];
        ax += d * bl(u); ay += d * bh(u);
    }
    ax += __shfl_down(ax, 32); ay += __shfl_down(ay, 32);
    ax += __shfl_down(ax, 16); ay += __shfl_down(ay, 16);
    if (q == 0) {
        float dn = dinv[n];
        unsigned un = g2u[(size_t)n * 16 + fo];
        ax += dn * bl(un); ay += dn * bh(un);   // self loop
        float2 bb = *(const float2*)&b2[2 * fo];
        float2 o = {dn * ax + bb.x, dn * ay + bb.y};
        *(float2*)&outp[(size_t)n * 32 + 2 * fo] = o;
    }
}

static inline size_t align256(size_t x) { return (x + 255) & ~(size_t)255; }

extern "C" void kernel_launch(void* const* d_in, const int* in_sizes, int n_in,
                              void* d_out, int out_size, void* d_ws, size_t ws_size,
                              hipStream_t stream) {
    const float* x  = (const float*)d_in[0];
    const int*   ei = (const int*)d_in[1];
    const float* W1 = (const float*)d_in[2];
    const float* b1 = (const float*)d_in[3];
    const float* W2 = (const float*)d_in[4];
    const float* b2 = (const float*)d_in[5];
    float* out = (float*)d_out;

    const int* src = ei;
    const int* dst = ei + N_EDGES;

    // workspace layout (peak ~47 MB, proven safe)
    char* ws = (char*)d_ws;
    size_t off = 0;
    int* gcur = (int*)(ws + off);              off = align256(off + NBUCK * 4);
    unsigned int* binned = (unsigned int*)(ws + off);
                                               off = align256(off + (size_t)NBUCK * CAP * 4);
    int* csr = (int*)(ws + off);               off = align256(off + (size_t)NBUCK * CAP * 4);
    int* rs  = (int*)(ws + off);               off = align256(off + (size_t)N_NODES * 4);
    int* re  = (int*)(ws + off);               off = align256(off + (size_t)N_NODES * 4);
    float* dinv = (float*)(ws + off);          off = align256(off + (size_t)N_NODES * 4);
    unsigned int* h1u = (unsigned int*)(ws + off);
                                               off = align256(off + (size_t)N_NODES * 32 * 4);
    float* h2 = (float*)(ws + off);            off = align256(off + (size_t)N_NODES * HID * 4);
    unsigned int* g2u = h1u;  // reuse; h1u dead after agg64

    hipMemsetAsync(gcur, 0, NBUCK * 4, stream);
    k_bin<<<BIN_BLOCKS, 256, 0, stream>>>(src, dst, gcur, binned);
    k_csr_gemm1<<<NBUCK + N_NODES / 128, 256, 0, stream>>>(binned, gcur, csr, rs, re,
                                                           dinv, x, W1, h1u);
    k_agg64<<<N_NODES / 4, 256, 0, stream>>>(h1u, csr, rs, re, dinv, b1, h2);
    k_gemm2<<<N_NODES / 64, 256, 0, stream>>>(h2, W2, g2u);
    k_agg32<<<N_NODES / 4, 256, 0, stream>>>(g2u, csr, rs, re, dinv, b2, out);
}